// Round 6
// baseline (697.278 us; speedup 1.0000x reference)
//
#include <hip/hip_runtime.h>
#include <hip/hip_bf16.h>

typedef __attribute__((ext_vector_type(8))) short bf16x8;
typedef __attribute__((ext_vector_type(4))) float f32x4;

#define SEQ 2048
#define DMODEL 1024
#define NH 16
#define HD 64
#define BATCH 4
#define BHTOT 64          // BATCH*NH
#define BS 8192           // BATCH*SEQ
#define QKV_ELEMS 8388608 // BS*DMODEL

// SCALE = 8 (sqrt(64)); softmax done in exp2 domain: C2 = (1/8)*log2(e)
#define C2EXP 0.1803368801111244f

__device__ __forceinline__ ushort f2bf(float f) {
  union { float f; unsigned u; } v; v.f = f;
  unsigned r = (v.u + 0x7FFFu + ((v.u >> 16) & 1u)) >> 16;
  return (ushort)r;
}

#if __has_builtin(__builtin_amdgcn_exp2f)
#define EXP2F(x) __builtin_amdgcn_exp2f(x)
#else
#define EXP2F(x) exp2f(x)
#endif

// ---------------- weight f32 -> bf16 convert ----------------
__global__ __launch_bounds__(256) void convert_w(
    const float* __restrict__ w0, const float* __restrict__ w1,
    const float* __restrict__ w2, ushort* __restrict__ out) {
  const float* src = blockIdx.y == 0 ? w0 : (blockIdx.y == 1 ? w1 : w2);
  size_t e = ((size_t)blockIdx.x * 256 + threadIdx.x) * 4;
  float4 v = *(const float4*)(src + e);
  ushort4 o = { f2bf(v.x), f2bf(v.y), f2bf(v.z), f2bf(v.w) };
  *(ushort4*)(out + (size_t)blockIdx.y * 1048576 + e) = o;
}

// ---------------- QKV projection GEMM ----------------
// out[m][n] = sum_k X[m][k] * W[n][k] + bias[n]
// Q,K stored bf16 [B,H,S,HD]; V stored TRANSPOSED bf16 [B,H,HD,S] so the
// attention PV B-fragment is a direct contiguous global load (no LDS transpose).
__global__ __launch_bounds__(256) void qkv_gemm(
    const float* __restrict__ x0, const float* __restrict__ x1, const float* __restrict__ x2,
    const ushort* __restrict__ Wb,
    const float* __restrict__ bq, const float* __restrict__ bk, const float* __restrict__ bv,
    ushort* __restrict__ qkv) {
  __shared__ ushort sA[128][40];  // +8 pad: row stride 80B -> 2-way bank alias (free)
  __shared__ ushort sB[128][40];

  const int z = blockIdx.z;
  const float* X = z == 0 ? x0 : (z == 1 ? x1 : x2);
  const ushort* W = Wb + (size_t)z * 1048576;
  const float* bias = z == 0 ? bq : (z == 1 ? bk : bv);
  ushort* out = qkv + (size_t)z * QKV_ELEMS;

  const int t = threadIdx.x;
  const int m0 = blockIdx.x * 128;
  const int n0 = blockIdx.y * 128;
  const int w = t >> 6, l = t & 63, lr = l & 15, lhi = l >> 4;
  const int wr = (w >> 1) * 64, wc = (w & 1) * 64;

  f32x4 acc[4][4];
#pragma unroll
  for (int i = 0; i < 4; i++)
#pragma unroll
    for (int j = 0; j < 4; j++) acc[i][j] = (f32x4){0.f, 0.f, 0.f, 0.f};

  for (int k0 = 0; k0 < DMODEL; k0 += 32) {
#pragma unroll
    for (int i = 0; i < 4; i++) {
      int e = i * 256 + t;
      int row = e >> 3, col = (e & 7) * 4;
      float4 a = *(const float4*)(X + (size_t)(m0 + row) * DMODEL + k0 + col);
      ushort4 ab = { f2bf(a.x), f2bf(a.y), f2bf(a.z), f2bf(a.w) };
      *(ushort4*)(&sA[row][col]) = ab;
      ushort4 bb = *(const ushort4*)(W + (size_t)(n0 + row) * DMODEL + k0 + col);
      *(ushort4*)(&sB[row][col]) = bb;
    }
    __syncthreads();
    bf16x8 af[4], bfr[4];
#pragma unroll
    for (int mi = 0; mi < 4; mi++) af[mi] = *(const bf16x8*)(&sA[wr + mi * 16 + lr][lhi * 8]);
#pragma unroll
    for (int ni = 0; ni < 4; ni++) bfr[ni] = *(const bf16x8*)(&sB[wc + ni * 16 + lr][lhi * 8]);
#pragma unroll
    for (int mi = 0; mi < 4; mi++)
#pragma unroll
      for (int ni = 0; ni < 4; ni++)
        acc[mi][ni] = __builtin_amdgcn_mfma_f32_16x16x32_bf16(af[mi], bfr[ni], acc[mi][ni], 0, 0, 0);
    __syncthreads();
  }

  // epilogue: C layout col=lane&15, row=(lane>>4)*4+reg
  if (z == 2) {
    // V^T layout [B,H,HD,S]: pack 4 consecutive s into one 8B store
#pragma unroll
    for (int mi = 0; mi < 4; mi++) {
#pragma unroll
      for (int ni = 0; ni < 4; ni++) {
        int col = n0 + wc + ni * 16 + lr;
        float bsv = bias[col];
        int h = col >> 6, hd = col & 63;
        int row0 = m0 + wr + mi * 16 + lhi * 4;
        int b = row0 >> 11, s0 = row0 & 2047;
        ushort ov[4];
#pragma unroll
        for (int r = 0; r < 4; r++) ov[r] = f2bf(acc[mi][ni][r] + bsv);
        *(uint2*)(out + ((size_t)(b * NH + h) * HD + hd) * SEQ + s0) = *(uint2*)ov;
      }
    }
  } else {
#pragma unroll
    for (int mi = 0; mi < 4; mi++) {
#pragma unroll
      for (int ni = 0; ni < 4; ni++) {
        int col = n0 + wc + ni * 16 + lr;
        float bsv = bias[col];
        int h = col >> 6, hd = col & 63;
#pragma unroll
        for (int r = 0; r < 4; r++) {
          int row = m0 + wr + mi * 16 + lhi * 4 + r;
          int b = row >> 11, s = row & 2047;
          float vv = acc[mi][ni][r] + bsv;
          out[(((size_t)(b * NH + h)) * SEQ + s) * HD + hd] = f2bf(vv);
        }
      }
    }
  }
}

// ---------------- flash attention ----------------
// qkv: bf16 [Q: B,H,S,HD][K: B,H,S,HD][V^T: B,H,HD,S]; out: f32 [B,S,D]
// Register-pipelined: K frags for tile t+1 are issued right after tile t's
// QK^T consumes them (latency hidden under softmax+PV); V^T frags for t+1
// issued after tile t's PV (hidden under next QK^T+softmax). No block LDS,
// no barriers; P goes through a wave-private LDS buffer only.
__global__ __launch_bounds__(256) void attn_kernel(const ushort* __restrict__ qkv,
                                                   float* __restrict__ out) {
  __shared__ unsigned Pl[4][16 * 36]; // per-wave P: [q][kv-pairs], row stride 144B

  // XCD-aware swizzle: 2048 blocks, 8 XCDs -> 256 consecutive bids per XCD,
  // so all 32 q-tiles of a head hit the same XCD L2 (~2 MB resident working set).
  const int rb = blockIdx.x;
  const int bid = (rb & 7) * 256 + (rb >> 3);
  const int bh = bid >> 5, qt = bid & 31;
  const int q0 = qt * 64;
  const int t = threadIdx.x, w = t >> 6, l = t & 63, lr = l & 15, lhi = l >> 4;

  const ushort* q = qkv;
  const ushort* k = qkv + QKV_ELEMS;
  const ushort* vt = qkv + 2 * (size_t)QKV_ELEMS;
  const size_t base = (size_t)bh * SEQ * HD;
  unsigned* Plw = &Pl[w][0];

  // hoist Q fragments (B-operand of swapped QK^T: col=q=l&15, k=(l>>4)*8..+8)
  bf16x8 aq[2];
  {
    int qrow = q0 + w * 16 + lr;
#pragma unroll
    for (int kk = 0; kk < 2; kk++)
      aq[kk] = *(const bf16x8*)(q + base + (size_t)qrow * HD + kk * 32 + lhi * 8);
  }

  // per-lane invariant bases
  const ushort* kb = k + base + (size_t)lr * HD + lhi * 8;
  const ushort* vb = vt + base + (size_t)lr * SEQ + lhi * 8;

  float m2 = -1e30f, lsum = 0.f;   // per-q (q = lr) state, replicated across lhi
  f32x4 acc_o[4];
#pragma unroll
  for (int i = 0; i < 4; i++) acc_o[i] = (f32x4){0.f, 0.f, 0.f, 0.f};

  // prologue: issue tile-0 K and V^T fragment loads
  bf16x8 kf[8], vf[8];
#pragma unroll
  for (int nb = 0; nb < 4; nb++)
#pragma unroll
    for (int kk = 0; kk < 2; kk++)
      kf[nb * 2 + kk] = *(const bf16x8*)(kb + (size_t)(nb * 16) * HD + kk * 32);
#pragma unroll
  for (int nbh = 0; nbh < 4; nbh++)
#pragma unroll
    for (int kk = 0; kk < 2; kk++)
      vf[nbh * 2 + kk] = *(const bf16x8*)(vb + (size_t)(nbh * 16) * SEQ + kk * 32);

  for (int tile = 0; tile < SEQ / 64; tile++) {
    const int kvn = ((tile + 1) & 31) * 64;  // next tile base (wraps; wrap load unused)

    // QK^T (swapped): sc[nb][r] = S[q=lr][kv=nb*16+lhi*4+r]
    f32x4 sc[4];
#pragma unroll
    for (int nb = 0; nb < 4; nb++) sc[nb] = (f32x4){0.f, 0.f, 0.f, 0.f};
#pragma unroll
    for (int nb = 0; nb < 4; nb++)
#pragma unroll
      for (int kk = 0; kk < 2; kk++)
        sc[nb] = __builtin_amdgcn_mfma_f32_16x16x32_bf16(kf[nb * 2 + kk], aq[kk], sc[nb], 0, 0, 0);

    // re-issue K loads for next tile (latency hidden under softmax + PV)
#pragma unroll
    for (int nb = 0; nb < 4; nb++)
#pragma unroll
      for (int kk = 0; kk < 2; kk++)
        kf[nb * 2 + kk] = *(const bf16x8*)(kb + (size_t)(kvn + nb * 16) * HD + kk * 32);

    // online softmax: in-lane partial max (one q row) + 2 shfl_xor across lhi
    float tm = sc[0][0];
#pragma unroll
    for (int nb = 0; nb < 4; nb++)
#pragma unroll
      for (int r = 0; r < 4; r++) tm = fmaxf(tm, sc[nb][r]);
    tm *= C2EXP;
    tm = fmaxf(tm, __shfl_xor(tm, 16));
    tm = fmaxf(tm, __shfl_xor(tm, 32));
    if (__any(tm > m2 + 8.f)) {   // defer-max: P bounded by 2^8
      float mn = fmaxf(m2, tm);
      float alpha = EXP2F(m2 - mn);
      m2 = mn;
      lsum *= alpha;
#pragma unroll
      for (int r = 0; r < 4; r++) {
        float ar = __shfl(alpha, (lhi << 4) | (lhi * 4 + r));  // alpha of q=lhi*4+r
#pragma unroll
        for (int nbh = 0; nbh < 4; nbh++) acc_o[nbh][r] *= ar;
      }
    }

    // P = exp2(sc*C2 - m2), packed to bf16 pairs in-register
    float rs = 0.f;
    unsigned pk[8];
#pragma unroll
    for (int nb = 0; nb < 4; nb++) {
#pragma unroll
      for (int h = 0; h < 2; h++) {
        float p0 = EXP2F(sc[nb][2 * h] * C2EXP - m2);
        float p1 = EXP2F(sc[nb][2 * h + 1] * C2EXP - m2);
        rs += p0 + p1;
        pk[nb * 2 + h] = (unsigned)f2bf(p0) | ((unsigned)f2bf(p1) << 16);
      }
    }
    rs += __shfl_xor(rs, 16);
    rs += __shfl_xor(rs, 32);
    lsum += rs;

    // P -> wave-private LDS (8 packed u32 writes), read back as A-fragments
#pragma unroll
    for (int nb = 0; nb < 4; nb++)
#pragma unroll
      for (int h = 0; h < 2; h++)
        Plw[lr * 36 + nb * 8 + lhi * 2 + h] = pk[nb * 2 + h];

    bf16x8 ap[2];
#pragma unroll
    for (int kk = 0; kk < 2; kk++)
      ap[kk] = *(const bf16x8*)(Plw + lr * 36 + kk * 16 + lhi * 4);

    // PV: O += P * V  (B-frag = V^T, prefetched in registers)
#pragma unroll
    for (int nbh = 0; nbh < 4; nbh++)
#pragma unroll
      for (int kk = 0; kk < 2; kk++)
        acc_o[nbh] = __builtin_amdgcn_mfma_f32_16x16x32_bf16(ap[kk], vf[nbh * 2 + kk], acc_o[nbh], 0, 0, 0);

    // re-issue V^T loads for next tile (latency hidden under next QK^T+softmax)
#pragma unroll
    for (int nbh = 0; nbh < 4; nbh++)
#pragma unroll
      for (int kk = 0; kk < 2; kk++)
        vf[nbh * 2 + kk] = *(const bf16x8*)(vb + (size_t)(nbh * 16) * SEQ + kvn + kk * 32);
  }

  // epilogue: out[b][s][h*64+hd] = acc/lsum(q-row)
  const int b = bh >> 4, h = bh & 15;
  float inv[4];
#pragma unroll
  for (int r = 0; r < 4; r++) {
    float ls = __shfl(lsum, (lhi << 4) | (lhi * 4 + r));  // lsum of q=lhi*4+r
    inv[r] = 1.f / ls;
  }
#pragma unroll
  for (int nbh = 0; nbh < 4; nbh++) {
#pragma unroll
    for (int r = 0; r < 4; r++) {
      int s = q0 + w * 16 + lhi * 4 + r;
      out[((size_t)(b * SEQ + s)) * DMODEL + h * HD + nbh * 16 + lr] = acc_o[nbh][r] * inv[r];
    }
  }
}

extern "C" void kernel_launch(void* const* d_in, const int* in_sizes, int n_in,
                              void* d_out, int out_size, void* d_ws, size_t ws_size,
                              hipStream_t stream) {
  const float* query = (const float*)d_in[0];
  const float* key_  = (const float*)d_in[1];
  const float* value = (const float*)d_in[2];
  const float* Wq = (const float*)d_in[3];
  const float* bq = (const float*)d_in[4];
  const float* Wk = (const float*)d_in[5];
  const float* bk = (const float*)d_in[6];
  const float* Wv = (const float*)d_in[7];
  const float* bv = (const float*)d_in[8];

  ushort* Wb = (ushort*)d_ws;                       // 3 * 1M bf16
  ushort* qkv = Wb + 3u * 1048576u;                 // 3 * 8.39M bf16

  convert_w<<<dim3(1024, 3), 256, 0, stream>>>(Wq, Wk, Wv, Wb);
  qkv_gemm<<<dim3(64, 8, 3), 256, 0, stream>>>(query, key_, value, Wb, bq, bk, bv, qkv);
  attn_kernel<<<dim3(BHTOT * (SEQ / 64)), 256, 0, stream>>>(qkv, (float*)d_out);
}

// Round 7
// 278.428 us; speedup vs baseline: 2.5043x; 2.5043x over previous
//
#include <hip/hip_runtime.h>
#include <hip/hip_bf16.h>

typedef __attribute__((ext_vector_type(8))) short bf16x8;
typedef __attribute__((ext_vector_type(4))) float f32x4;

#define SEQ 2048
#define DMODEL 1024
#define NH 16
#define HD 64
#define BATCH 4
#define BHTOT 64          // BATCH*NH
#define BS 8192           // BATCH*SEQ
#define QKV_ELEMS 8388608 // BS*DMODEL

// SCALE = 8 (sqrt(64)); softmax done in exp2 domain: C2 = (1/8)*log2(e)
#define C2EXP 0.1803368801111244f

__device__ __forceinline__ ushort f2bf(float f) {
  union { float f; unsigned u; } v; v.f = f;
  unsigned r = (v.u + 0x7FFFu + ((v.u >> 16) & 1u)) >> 16;
  return (ushort)r;
}

#if __has_builtin(__builtin_amdgcn_exp2f)
#define EXP2F(x) __builtin_amdgcn_exp2f(x)
#else
#define EXP2F(x) exp2f(x)
#endif

// ---------------- weight f32 -> bf16 convert ----------------
__global__ __launch_bounds__(256) void convert_w(
    const float* __restrict__ w0, const float* __restrict__ w1,
    const float* __restrict__ w2, ushort* __restrict__ out) {
  const float* src = blockIdx.y == 0 ? w0 : (blockIdx.y == 1 ? w1 : w2);
  size_t e = ((size_t)blockIdx.x * 256 + threadIdx.x) * 4;
  float4 v = *(const float4*)(src + e);
  ushort4 o = { f2bf(v.x), f2bf(v.y), f2bf(v.z), f2bf(v.w) };
  *(ushort4*)(out + (size_t)blockIdx.y * 1048576 + e) = o;
}

// ---------------- QKV projection GEMM ----------------
// out[m][n] = sum_k X[m][k] * W[n][k] + bias[n], all stored bf16 [B,H,S,HD].
// (V^T global layout reverted: its scattered 8B/4KB-stride epilogue stores cost
//  ~120 us in R4-R6. The V transpose now happens in attn's LDS staging.)
__global__ __launch_bounds__(256) void qkv_gemm(
    const float* __restrict__ x0, const float* __restrict__ x1, const float* __restrict__ x2,
    const ushort* __restrict__ Wb,
    const float* __restrict__ bq, const float* __restrict__ bk, const float* __restrict__ bv,
    ushort* __restrict__ qkv) {
  __shared__ ushort sA[128][40];  // +8 pad: row stride 80B -> 2-way bank alias (free)
  __shared__ ushort sB[128][40];

  const int z = blockIdx.z;
  const float* X = z == 0 ? x0 : (z == 1 ? x1 : x2);
  const ushort* W = Wb + (size_t)z * 1048576;
  const float* bias = z == 0 ? bq : (z == 1 ? bk : bv);
  ushort* out = qkv + (size_t)z * QKV_ELEMS;

  const int t = threadIdx.x;
  const int m0 = blockIdx.x * 128;
  const int n0 = blockIdx.y * 128;
  const int w = t >> 6, l = t & 63, lr = l & 15, lhi = l >> 4;
  const int wr = (w >> 1) * 64, wc = (w & 1) * 64;

  f32x4 acc[4][4];
#pragma unroll
  for (int i = 0; i < 4; i++)
#pragma unroll
    for (int j = 0; j < 4; j++) acc[i][j] = (f32x4){0.f, 0.f, 0.f, 0.f};

  for (int k0 = 0; k0 < DMODEL; k0 += 32) {
#pragma unroll
    for (int i = 0; i < 4; i++) {
      int e = i * 256 + t;
      int row = e >> 3, col = (e & 7) * 4;
      float4 a = *(const float4*)(X + (size_t)(m0 + row) * DMODEL + k0 + col);
      ushort4 ab = { f2bf(a.x), f2bf(a.y), f2bf(a.z), f2bf(a.w) };
      *(ushort4*)(&sA[row][col]) = ab;
      ushort4 bb = *(const ushort4*)(W + (size_t)(n0 + row) * DMODEL + k0 + col);
      *(ushort4*)(&sB[row][col]) = bb;
    }
    __syncthreads();
    bf16x8 af[4], bfr[4];
#pragma unroll
    for (int mi = 0; mi < 4; mi++) af[mi] = *(const bf16x8*)(&sA[wr + mi * 16 + lr][lhi * 8]);
#pragma unroll
    for (int ni = 0; ni < 4; ni++) bfr[ni] = *(const bf16x8*)(&sB[wc + ni * 16 + lr][lhi * 8]);
#pragma unroll
    for (int mi = 0; mi < 4; mi++)
#pragma unroll
      for (int ni = 0; ni < 4; ni++)
        acc[mi][ni] = __builtin_amdgcn_mfma_f32_16x16x32_bf16(af[mi], bfr[ni], acc[mi][ni], 0, 0, 0);
    __syncthreads();
  }

  // epilogue: C layout col=lane&15, row=(lane>>4)*4+reg
#pragma unroll
  for (int mi = 0; mi < 4; mi++) {
#pragma unroll
    for (int ni = 0; ni < 4; ni++) {
      int col = n0 + wc + ni * 16 + lr;
      float bsv = bias[col];
      int h = col >> 6, hd = col & 63;
#pragma unroll
      for (int r = 0; r < 4; r++) {
        int row = m0 + wr + mi * 16 + lhi * 4 + r;
        int b = row >> 11, s = row & 2047;
        float vv = acc[mi][ni][r] + bsv;
        out[(((size_t)(b * NH + h)) * SEQ + s) * HD + hd] = f2bf(vv);
      }
    }
  }
}

// ---------------- flash attention ----------------
// qkv: bf16 [Q][K][V] each [B,H,S,HD]; out: f32 [B,S,D]
// Double-buffered LDS pipeline for BOTH K and V (one tile ahead), T14 split:
// global loads issued at loop top, ds_writes after PV so the vmcnt wait hides
// under ~600 cyc of MFMA+softmax. One barrier per tile. V is transposed during
// the staging scatter (R1's conflict-free column-write scheme).
__global__ __launch_bounds__(256) void attn_kernel(const ushort* __restrict__ qkv,
                                                   float* __restrict__ out) {
  __shared__ ushort Kt[2][64][72];    // K tile  [kv][hd], stride 144B
  __shared__ ushort Vt[2][64][72];    // V^T tile [hd][kv], stride 144B
  __shared__ unsigned Pl[4][16 * 36]; // per-wave P: [q][kv-pairs], row stride 144B

  // XCD-aware swizzle: 2048 blocks, 8 XCDs -> 256 consecutive bids per XCD,
  // so all 32 q-tiles of a head hit the same XCD L2.
  const int rb = blockIdx.x;
  const int bid = (rb & 7) * 256 + (rb >> 3);
  const int bh = bid >> 5, qt = bid & 31;
  const int q0 = qt * 64;
  const int t = threadIdx.x, w = t >> 6, l = t & 63, lr = l & 15, lhi = l >> 4;

  const ushort* q = qkv;
  const ushort* k = qkv + QKV_ELEMS;
  const ushort* v = qkv + 2 * (size_t)QKV_ELEMS;
  const size_t base = (size_t)bh * SEQ * HD;
  unsigned* Plw = &Pl[w][0];

  // staging coords
  const int krow = t >> 3, kcol = (t & 7) * 8;  // K: rows 0..31 (i=0) / 32..63 (i=1)
  const int skv = t & 63;                        // V: kv row this thread loads
  const int shb = (t >> 6) * 8;                  // V: hd block base, +32 on i=1

  // hoist Q fragments (B-operand of swapped QK^T: col=q=l&15, k=(l>>4)*8..+8)
  bf16x8 aq[2];
  {
    int qrow = q0 + w * 16 + lr;
#pragma unroll
    for (int kk = 0; kk < 2; kk++)
      aq[kk] = *(const bf16x8*)(q + base + (size_t)qrow * HD + kk * 32 + lhi * 8);
  }

  float m2 = -1e30f, lsum = 0.f;   // per-q (q = lr) state, replicated across lhi
  f32x4 acc_o[4];
#pragma unroll
  for (int i = 0; i < 4; i++) acc_o[i] = (f32x4){0.f, 0.f, 0.f, 0.f};

  // prologue: stage tile 0 into buf 0
  {
#pragma unroll
    for (int i = 0; i < 2; i++) {
      bf16x8 gk = *(const bf16x8*)(k + base + (size_t)(i * 32 + krow) * HD + kcol);
      *(bf16x8*)(&Kt[0][i * 32 + krow][kcol]) = gk;
      bf16x8 gv = *(const bf16x8*)(v + base + (size_t)skv * HD + shb + i * 32);
#pragma unroll
      for (int j = 0; j < 8; j++) Vt[0][shb + i * 32 + j][skv] = ((ushort)gv[j]);
    }
  }
  __syncthreads();

  for (int tile = 0; tile < SEQ / 64; tile++) {
    const int cur = tile & 1, nxt = cur ^ 1;
    const int kvn = ((tile + 1) & 31) * 64;  // next tile base (wraps; wrap data unused)

    // T14 issue-early: global loads for tile+1 (latency hides under this tile's compute)
    bf16x8 gk[2], gv[2];
#pragma unroll
    for (int i = 0; i < 2; i++) {
      gk[i] = *(const bf16x8*)(k + base + (size_t)(kvn + i * 32 + krow) * HD + kcol);
      gv[i] = *(const bf16x8*)(v + base + (size_t)(kvn + skv) * HD + shb + i * 32);
    }

    // QK^T (swapped): sc[nb][r] = S[q=lr][kv=nb*16+lhi*4+r], K frags from LDS
    f32x4 sc[4];
#pragma unroll
    for (int nb = 0; nb < 4; nb++) sc[nb] = (f32x4){0.f, 0.f, 0.f, 0.f};
#pragma unroll
    for (int nb = 0; nb < 4; nb++)
#pragma unroll
      for (int kk = 0; kk < 2; kk++) {
        bf16x8 bk = *(const bf16x8*)(&Kt[cur][nb * 16 + lr][kk * 32 + lhi * 8]);
        sc[nb] = __builtin_amdgcn_mfma_f32_16x16x32_bf16(bk, aq[kk], sc[nb], 0, 0, 0);
      }

    // online softmax: in-lane partial max (one q row) + 2 shfl_xor across lhi
    float tm = sc[0][0];
#pragma unroll
    for (int nb = 0; nb < 4; nb++)
#pragma unroll
      for (int r = 0; r < 4; r++) tm = fmaxf(tm, sc[nb][r]);
    tm *= C2EXP;
    tm = fmaxf(tm, __shfl_xor(tm, 16));
    tm = fmaxf(tm, __shfl_xor(tm, 32));
    if (__any(tm > m2 + 8.f)) {   // defer-max: P bounded by 2^8
      float mn = fmaxf(m2, tm);
      float alpha = EXP2F(m2 - mn);
      m2 = mn;
      lsum *= alpha;
#pragma unroll
      for (int r = 0; r < 4; r++) {
        float ar = __shfl(alpha, (lhi << 4) | (lhi * 4 + r));  // alpha of q=lhi*4+r
#pragma unroll
        for (int nbh = 0; nbh < 4; nbh++) acc_o[nbh][r] *= ar;
      }
    }

    // P = exp2(sc*C2 - m2), packed to bf16 pairs in-register
    float rs = 0.f;
    unsigned pk[8];
#pragma unroll
    for (int nb = 0; nb < 4; nb++) {
#pragma unroll
      for (int hh = 0; hh < 2; hh++) {
        float p0 = EXP2F(sc[nb][2 * hh] * C2EXP - m2);
        float p1 = EXP2F(sc[nb][2 * hh + 1] * C2EXP - m2);
        rs += p0 + p1;
        pk[nb * 2 + hh] = (unsigned)f2bf(p0) | ((unsigned)f2bf(p1) << 16);
      }
    }
    rs += __shfl_xor(rs, 16);
    rs += __shfl_xor(rs, 32);
    lsum += rs;

    // P -> wave-private LDS (8 packed u32 writes), read back as A-fragments
#pragma unroll
    for (int nb = 0; nb < 4; nb++)
#pragma unroll
      for (int hh = 0; hh < 2; hh++)
        Plw[lr * 36 + nb * 8 + lhi * 2 + hh] = pk[nb * 2 + hh];

    bf16x8 ap[2];
#pragma unroll
    for (int kk = 0; kk < 2; kk++)
      ap[kk] = *(const bf16x8*)(Plw + lr * 36 + kk * 16 + lhi * 4);

    // PV: O += P * V  (B-frag = V^T from LDS)
#pragma unroll
    for (int nbh = 0; nbh < 4; nbh++)
#pragma unroll
      for (int kk = 0; kk < 2; kk++) {
        bf16x8 bv = *(const bf16x8*)(&Vt[cur][nbh * 16 + lr][kk * 32 + lhi * 8]);
        acc_o[nbh] = __builtin_amdgcn_mfma_f32_16x16x32_bf16(ap[kk], bv, acc_o[nbh], 0, 0, 0);
      }

    // T14 write-late: vmcnt wait lands here, after the tile's compute
#pragma unroll
    for (int i = 0; i < 2; i++) {
      *(bf16x8*)(&Kt[nxt][i * 32 + krow][kcol]) = gk[i];
#pragma unroll
      for (int j = 0; j < 8; j++) Vt[nxt][shb + i * 32 + j][skv] = ((ushort)gv[i][j]);
    }
    __syncthreads();
  }

  // epilogue: out[b][s][h*64+hd] = acc/lsum(q-row)
  const int b = bh >> 4, h = bh & 15;
  float inv[4];
#pragma unroll
  for (int r = 0; r < 4; r++) {
    float ls = __shfl(lsum, (lhi << 4) | (lhi * 4 + r));  // lsum of q=lhi*4+r
    inv[r] = 1.f / ls;
  }
#pragma unroll
  for (int nbh = 0; nbh < 4; nbh++) {
#pragma unroll
    for (int r = 0; r < 4; r++) {
      int s = q0 + w * 16 + lhi * 4 + r;
      out[((size_t)(b * SEQ + s)) * DMODEL + h * HD + nbh * 16 + lr] = acc_o[nbh][r] * inv[r];
    }
  }
}

extern "C" void kernel_launch(void* const* d_in, const int* in_sizes, int n_in,
                              void* d_out, int out_size, void* d_ws, size_t ws_size,
                              hipStream_t stream) {
  const float* query = (const float*)d_in[0];
  const float* key_  = (const float*)d_in[1];
  const float* value = (const float*)d_in[2];
  const float* Wq = (const float*)d_in[3];
  const float* bq = (const float*)d_in[4];
  const float* Wk = (const float*)d_in[5];
  const float* bk = (const float*)d_in[6];
  const float* Wv = (const float*)d_in[7];
  const float* bv = (const float*)d_in[8];

  ushort* Wb = (ushort*)d_ws;                       // 3 * 1M bf16
  ushort* qkv = Wb + 3u * 1048576u;                 // 3 * 8.39M bf16

  convert_w<<<dim3(1024, 3), 256, 0, stream>>>(Wq, Wk, Wv, Wb);
  qkv_gemm<<<dim3(64, 8, 3), 256, 0, stream>>>(query, key_, value, Wb, bq, bk, bv, qkv);
  attn_kernel<<<dim3(BHTOT * (SEQ / 64)), 256, 0, stream>>>(qkv, (float*)d_out);
}

// Round 8
// 232.747 us; speedup vs baseline: 2.9959x; 1.1963x over previous
//
#include <hip/hip_runtime.h>
#include <hip/hip_bf16.h>

typedef __attribute__((ext_vector_type(8))) short bf16x8;
typedef __attribute__((ext_vector_type(4))) float f32x4;
typedef __attribute__((ext_vector_type(16))) float f32x16;

#define SEQ 2048
#define DMODEL 1024
#define NH 16
#define HD 64
#define BATCH 4
#define BHTOT 64          // BATCH*NH
#define BS 8192           // BATCH*SEQ
#define QKV_ELEMS 8388608 // BS*DMODEL

// SCALE = 8 (sqrt(64)); softmax done in exp2 domain: C2 = (1/8)*log2(e)
#define C2EXP 0.1803368801111244f

__device__ __forceinline__ ushort f2bf(float f) {
  union { float f; unsigned u; } v; v.f = f;
  unsigned r = (v.u + 0x7FFFu + ((v.u >> 16) & 1u)) >> 16;
  return (ushort)r;
}

__device__ __forceinline__ unsigned pkbf(float a, float b) {
  union { __hip_bfloat162 h; unsigned u; } cv;
  cv.h = __float22bfloat162_rn(make_float2(a, b));
  return cv.u;
}

#if __has_builtin(__builtin_amdgcn_exp2f)
#define EXP2F(x) __builtin_amdgcn_exp2f(x)
#else
#define EXP2F(x) exp2f(x)
#endif

// ---------------- weight f32 -> bf16 convert ----------------
__global__ __launch_bounds__(256) void convert_w(
    const float* __restrict__ w0, const float* __restrict__ w1,
    const float* __restrict__ w2, ushort* __restrict__ out) {
  const float* src = blockIdx.y == 0 ? w0 : (blockIdx.y == 1 ? w1 : w2);
  size_t e = ((size_t)blockIdx.x * 256 + threadIdx.x) * 4;
  float4 v = *(const float4*)(src + e);
  ushort4 o = { f2bf(v.x), f2bf(v.y), f2bf(v.z), f2bf(v.w) };
  *(ushort4*)(out + (size_t)blockIdx.y * 1048576 + e) = o;
}

// ---------------- QKV projection GEMM ----------------
// out[m][n] = sum_k X[m][k] * W[n][k] + bias[n], all stored bf16 [B,H,S,HD].
__global__ __launch_bounds__(256) void qkv_gemm(
    const float* __restrict__ x0, const float* __restrict__ x1, const float* __restrict__ x2,
    const ushort* __restrict__ Wb,
    const float* __restrict__ bq, const float* __restrict__ bk, const float* __restrict__ bv,
    ushort* __restrict__ qkv) {
  __shared__ ushort sA[128][40];  // +8 pad: row stride 80B -> 2-way bank alias (free)
  __shared__ ushort sB[128][40];

  const int z = blockIdx.z;
  const float* X = z == 0 ? x0 : (z == 1 ? x1 : x2);
  const ushort* W = Wb + (size_t)z * 1048576;
  const float* bias = z == 0 ? bq : (z == 1 ? bk : bv);
  ushort* out = qkv + (size_t)z * QKV_ELEMS;

  const int t = threadIdx.x;
  const int m0 = blockIdx.x * 128;
  const int n0 = blockIdx.y * 128;
  const int w = t >> 6, l = t & 63, lr = l & 15, lhi = l >> 4;
  const int wr = (w >> 1) * 64, wc = (w & 1) * 64;

  f32x4 acc[4][4];
#pragma unroll
  for (int i = 0; i < 4; i++)
#pragma unroll
    for (int j = 0; j < 4; j++) acc[i][j] = (f32x4){0.f, 0.f, 0.f, 0.f};

  for (int k0 = 0; k0 < DMODEL; k0 += 32) {
#pragma unroll
    for (int i = 0; i < 4; i++) {
      int e = i * 256 + t;
      int row = e >> 3, col = (e & 7) * 4;
      float4 a = *(const float4*)(X + (size_t)(m0 + row) * DMODEL + k0 + col);
      ushort4 ab = { f2bf(a.x), f2bf(a.y), f2bf(a.z), f2bf(a.w) };
      *(ushort4*)(&sA[row][col]) = ab;
      ushort4 bb = *(const ushort4*)(W + (size_t)(n0 + row) * DMODEL + k0 + col);
      *(ushort4*)(&sB[row][col]) = bb;
    }
    __syncthreads();
    bf16x8 af[4], bfr[4];
#pragma unroll
    for (int mi = 0; mi < 4; mi++) af[mi] = *(const bf16x8*)(&sA[wr + mi * 16 + lr][lhi * 8]);
#pragma unroll
    for (int ni = 0; ni < 4; ni++) bfr[ni] = *(const bf16x8*)(&sB[wc + ni * 16 + lr][lhi * 8]);
#pragma unroll
    for (int mi = 0; mi < 4; mi++)
#pragma unroll
      for (int ni = 0; ni < 4; ni++)
        acc[mi][ni] = __builtin_amdgcn_mfma_f32_16x16x32_bf16(af[mi], bfr[ni], acc[mi][ni], 0, 0, 0);
    __syncthreads();
  }

  // epilogue: C layout col=lane&15, row=(lane>>4)*4+reg
#pragma unroll
  for (int mi = 0; mi < 4; mi++) {
#pragma unroll
    for (int ni = 0; ni < 4; ni++) {
      int col = n0 + wc + ni * 16 + lr;
      float bsv = bias[col];
      int h = col >> 6, hd = col & 63;
#pragma unroll
      for (int r = 0; r < 4; r++) {
        int row = m0 + wr + mi * 16 + lhi * 4 + r;
        int b = row >> 11, s = row & 2047;
        float vv = acc[mi][ni][r] + bsv;
        out[(((size_t)(b * NH + h)) * SEQ + s) * HD + hd] = f2bf(vv);
      }
    }
  }
}

// ---------------- flash attention (32x32x16 MFMA, in-register P) ----------------
// qkv: bf16 [Q][K][V] each [B,H,S,HD]; out: f32 [B,S,D]
// Each wave owns 32 q rows; block = 4 waves = 128 q. Swapped QK^T puts all of
// q=lane&31's scores in-lane -> softmax is in-lane + 1 shfl_xor(32). P is
// cvt_pk'ed to bf16 chunks that feed PV's A-fragment DIRECTLY: the MFMA k-axis
// is re-permuted (kv bits 2<->3 swapped) and V's LDS columns are stored in the
// same permuted order, so no cross-lane exchange and no P LDS roundtrip exist.
// K/V double-buffered in LDS, issue-early/write-late, one barrier per tile.
__global__ __launch_bounds__(256) void attn_kernel(const ushort* __restrict__ qkv,
                                                   float* __restrict__ out) {
  __shared__ ushort Kt[2][64][72];    // K tile  [kv][hd], stride 144B
  __shared__ ushort Vt[2][64][72];    // V^T tile [hd][kv'], kv' = bits2<->3 swapped

  // XCD-aware swizzle: 1024 blocks, 8 XCDs -> 128 consecutive bids per XCD.
  const int rb = blockIdx.x;
  const int bid = (rb & 7) * 128 + (rb >> 3);
  const int bh = bid >> 4, qt = bid & 15;
  const int q0 = qt * 128;
  const int t = threadIdx.x, w = t >> 6, l = t & 63;
  const int lq = l & 31, hi = l >> 5, hi8 = hi * 8;

  const ushort* q = qkv;
  const ushort* k = qkv + QKV_ELEMS;
  const ushort* v = qkv + 2 * (size_t)QKV_ELEMS;
  const size_t base = (size_t)bh * SEQ * HD;

  // staging coords (256 threads stage 64x64 K and V in 2 chunks each)
  const int krow = t >> 3, kcol = (t & 7) * 8;  // K rows 0..31 (+32 on i=1)
  const int skv = t & 63;                        // V source row
  const int skvp = (skv & 51) | ((skv & 4) << 1) | ((skv & 8) >> 1); // bits 2<->3
  const int shb = (t >> 6) * 8;                  // V hd base, +32 on i=1

  // hoist Q fragments (B-operand of swapped QK^T: col=q=lq, k=hd=hi*8+j+16*ks)
  bf16x8 aq[4];
  {
    int qrow = q0 + w * 32 + lq;
#pragma unroll
    for (int ks = 0; ks < 4; ks++)
      aq[ks] = *(const bf16x8*)(q + base + (size_t)qrow * HD + ks * 16 + hi8);
  }

  float m2 = -1e30f, lsum = 0.f;   // per-q (q = lq) state, replicated across hi
  f32x16 acc_o[2];
  acc_o[0] = (f32x16)(0.0f);
  acc_o[1] = (f32x16)(0.0f);

  // prologue: stage tile 0 into buf 0
#pragma unroll
  for (int i = 0; i < 2; i++) {
    bf16x8 gk = *(const bf16x8*)(k + base + (size_t)(i * 32 + krow) * HD + kcol);
    *(bf16x8*)(&Kt[0][i * 32 + krow][kcol]) = gk;
    bf16x8 gv = *(const bf16x8*)(v + base + (size_t)skv * HD + shb + i * 32);
#pragma unroll
    for (int j = 0; j < 8; j++) Vt[0][shb + i * 32 + j][skvp] = ((ushort)gv[j]);
  }
  __syncthreads();

  for (int tile = 0; tile < SEQ / 64; tile++) {
    const int cur = tile & 1, nxt = cur ^ 1;
    const int kvn = ((tile + 1) & 31) * 64;  // next tile base (wraps; wrap data unused)

    // T14 issue-early: global loads for tile+1
    bf16x8 gk[2], gv[2];
#pragma unroll
    for (int i = 0; i < 2; i++) {
      gk[i] = *(const bf16x8*)(k + base + (size_t)(kvn + i * 32 + krow) * HD + kcol);
      gv[i] = *(const bf16x8*)(v + base + (size_t)(kvn + skv) * HD + shb + i * 32);
    }

    // QK^T (swapped): sc[mt] holds S[kv=mt*32+rowpat][q=lq]
    f32x16 sc[2];
    sc[0] = (f32x16)(0.0f);
    sc[1] = (f32x16)(0.0f);
#pragma unroll
    for (int mt = 0; mt < 2; mt++)
#pragma unroll
      for (int ks = 0; ks < 4; ks++) {
        bf16x8 ak = *(const bf16x8*)(&Kt[cur][mt * 32 + lq][ks * 16 + hi8]);
        sc[mt] = __builtin_amdgcn_mfma_f32_32x32x16_bf16(ak, aq[ks], sc[mt], 0, 0, 0);
      }

    // online softmax: in-lane max over 32 scores + 1 shfl_xor(32)
    float tm = sc[0][0];
#pragma unroll
    for (int mt = 0; mt < 2; mt++)
#pragma unroll
      for (int r = 0; r < 16; r++) tm = fmaxf(tm, sc[mt][r]);
    tm *= C2EXP;
    tm = fmaxf(tm, __shfl_xor(tm, 32));
    if (__any(tm > m2 + 8.f)) {   // defer-max: P bounded by 2^8
      float mn = fmaxf(m2, tm);
      float alpha = EXP2F(m2 - mn);
      m2 = mn;
      lsum *= alpha;
#pragma unroll
      for (int r = 0; r < 16; r++) {
        int rowq = (r & 3) + 8 * (r >> 2) + 4 * hi;
        float ar = __shfl(alpha, (l & 32) | rowq);  // alpha of q=rowq
        acc_o[0][r] *= ar;
        acc_o[1][r] *= ar;
      }
    }

    // P = exp2(sc*C2 - m2) -> bf16 chunk pairs (kv-adjacent), fully in-register
    float rs = 0.f;
    unsigned c[2][8];
#pragma unroll
    for (int mt = 0; mt < 2; mt++)
#pragma unroll
      for (int i = 0; i < 8; i++) {
        float p0 = EXP2F(sc[mt][2 * i] * C2EXP - m2);
        float p1 = EXP2F(sc[mt][2 * i + 1] * C2EXP - m2);
        rs += p0 + p1;
        c[mt][i] = pkbf(p0, p1);
      }
    rs += __shfl_xor(rs, 32);
    lsum += rs;

    // PV: A = own chunks (k-axis permuted to lane-natural order),
    //     B = Vt with matching permuted columns (contiguous b128)
#pragma unroll
    for (int s = 0; s < 4; s++) {
      union { unsigned u[4]; bf16x8 v8; } ap;
#pragma unroll
      for (int j = 0; j < 4; j++) ap.u[j] = c[s >> 1][(s & 1) * 4 + j];
#pragma unroll
      for (int nt = 0; nt < 2; nt++) {
        bf16x8 bv = *(const bf16x8*)(&Vt[cur][nt * 32 + lq][s * 16 + hi8]);
        acc_o[nt] = __builtin_amdgcn_mfma_f32_32x32x16_bf16(ap.v8, bv, acc_o[nt], 0, 0, 0);
      }
    }

    // T14 write-late: stage tile+1 into the other buffer
#pragma unroll
    for (int i = 0; i < 2; i++) {
      *(bf16x8*)(&Kt[nxt][i * 32 + krow][kcol]) = gk[i];
#pragma unroll
      for (int j = 0; j < 8; j++) Vt[nxt][shb + i * 32 + j][skvp] = ((ushort)gv[i][j]);
    }
    __syncthreads();
  }

  // epilogue: out[b][s][h*64+hd] = acc/lsum(q-row)
  const int b = bh >> 4, h = bh & 15;
  float inv = 1.f / lsum;  // own q = lq
#pragma unroll
  for (int r = 0; r < 16; r++) {
    int rowq = (r & 3) + 8 * (r >> 2) + 4 * hi;
    float iv = __shfl(inv, (l & 32) | rowq);
    int s = q0 + w * 32 + rowq;
#pragma unroll
    for (int nt = 0; nt < 2; nt++)
      out[((size_t)(b * SEQ + s)) * DMODEL + h * HD + nt * 32 + lq] = acc_o[nt][r] * iv;
  }
}

extern "C" void kernel_launch(void* const* d_in, const int* in_sizes, int n_in,
                              void* d_out, int out_size, void* d_ws, size_t ws_size,
                              hipStream_t stream) {
  const float* query = (const float*)d_in[0];
  const float* key_  = (const float*)d_in[1];
  const float* value = (const float*)d_in[2];
  const float* Wq = (const float*)d_in[3];
  const float* bq = (const float*)d_in[4];
  const float* Wk = (const float*)d_in[5];
  const float* bk = (const float*)d_in[6];
  const float* Wv = (const float*)d_in[7];
  const float* bv = (const float*)d_in[8];

  ushort* Wb = (ushort*)d_ws;                       // 3 * 1M bf16
  ushort* qkv = Wb + 3u * 1048576u;                 // 3 * 8.39M bf16

  convert_w<<<dim3(1024, 3), 256, 0, stream>>>(Wq, Wk, Wv, Wb);
  qkv_gemm<<<dim3(64, 8, 3), 256, 0, stream>>>(query, key_, value, Wb, bq, bk, bv, qkv);
  attn_kernel<<<dim3(BHTOT * (SEQ / 128)), 256, 0, stream>>>(qkv, (float*)d_out);
}

// Round 9
// 205.988 us; speedup vs baseline: 3.3850x; 1.1299x over previous
//
#include <hip/hip_runtime.h>
#include <hip/hip_bf16.h>

typedef __attribute__((ext_vector_type(8))) short bf16x8;
typedef __attribute__((ext_vector_type(4))) float f32x4;
typedef __attribute__((ext_vector_type(16))) float f32x16;

#define SEQ 2048
#define DMODEL 1024
#define NH 16
#define HD 64
#define BATCH 4
#define BHTOT 64          // BATCH*NH
#define BS 8192           // BATCH*SEQ
#define QKV_ELEMS 8388608 // BS*DMODEL

// SCALE = 8 (sqrt(64)); softmax done in exp2 domain: C2 = (1/8)*log2(e)
#define C2EXP 0.1803368801111244f

__device__ __forceinline__ ushort f2bf(float f) {
  union { float f; unsigned u; } v; v.f = f;
  unsigned r = (v.u + 0x7FFFu + ((v.u >> 16) & 1u)) >> 16;
  return (ushort)r;
}

__device__ __forceinline__ unsigned pkbf(float a, float b) {
  union { __hip_bfloat162 h; unsigned u; } cv;
  cv.h = __float22bfloat162_rn(make_float2(a, b));
  return cv.u;
}

#if __has_builtin(__builtin_amdgcn_exp2f)
#define EXP2F(x) __builtin_amdgcn_exp2f(x)
#else
#define EXP2F(x) exp2f(x)
#endif

// async global->LDS, 16B per lane; LDS dest is wave-uniform base + lane*16
#define GLD16(gp, lp)                                                        \
  __builtin_amdgcn_global_load_lds(                                          \
      (const __attribute__((address_space(1))) void*)(gp),                   \
      (__attribute__((address_space(3))) void*)(lp), 16, 0, 0)

// ---------------- weight f32 -> bf16 convert ----------------
__global__ __launch_bounds__(256) void convert_w(
    const float* __restrict__ w0, const float* __restrict__ w1,
    const float* __restrict__ w2, ushort* __restrict__ out) {
  const float* src = blockIdx.y == 0 ? w0 : (blockIdx.y == 1 ? w1 : w2);
  size_t e = ((size_t)blockIdx.x * 256 + threadIdx.x) * 4;
  float4 v = *(const float4*)(src + e);
  ushort4 o = { f2bf(v.x), f2bf(v.y), f2bf(v.z), f2bf(v.w) };
  *(ushort4*)(out + (size_t)blockIdx.y * 1048576 + e) = o;
}

// ---------------- activation f32 -> bf16 convert ----------------
__global__ __launch_bounds__(256) void convert_x(
    const float* __restrict__ x0, const float* __restrict__ x1,
    const float* __restrict__ x2, ushort* __restrict__ out) {
  const float* src = blockIdx.y == 0 ? x0 : (blockIdx.y == 1 ? x1 : x2);
  size_t e = ((size_t)blockIdx.x * 256 + threadIdx.x) * 4;
  float4 v = *(const float4*)(src + e);
  ushort4 o = { f2bf(v.x), f2bf(v.y), f2bf(v.z), f2bf(v.w) };
  *(ushort4*)(out + (size_t)blockIdx.y * (size_t)QKV_ELEMS + e) = o;
}

// ---------------- QKV projection GEMM (m97 structure) ----------------
// A = Xb bf16 [z][8192][1024], B = Wb bf16 [z][1024][1024] (k-contiguous).
// 128x128 tile, BK=32, global_load_lds(16B) staging into LINEAR LDS with
// source-side XOR swizzle; read column XOR is lane-constant -> zero-cost.
// out bf16 [B,H,S,HD].
__global__ __launch_bounds__(256) void qkv_gemm_bf(
    const ushort* __restrict__ Xb, const ushort* __restrict__ Wb,
    const float* __restrict__ bq, const float* __restrict__ bk, const float* __restrict__ bv,
    ushort* __restrict__ qkv) {
  __shared__ ushort sA[128][32];  // linear: row stride 64B
  __shared__ ushort sB[128][32];

  const int z = blockIdx.z;
  const ushort* A = Xb + (size_t)z * QKV_ELEMS;
  const ushort* W = Wb + (size_t)z * 1048576;
  const float* bias = z == 0 ? bq : (z == 1 ? bk : bv);
  ushort* out = qkv + (size_t)z * QKV_ELEMS;

  const int t = threadIdx.x;
  const int m0 = blockIdx.x * 128;
  const int n0 = blockIdx.y * 128;
  const int w = t >> 6, l = t & 63, lr = l & 15, lhi = l >> 4;
  const int wr = (w >> 1) * 64, wc = (w & 1) * 64;

  // staging coords: wave w covers 16-row chunks c = 2w, 2w+1 of the 128-row tile
  const int rl = l >> 2;                         // 0..15 row-within-chunk
  const int scol = ((l & 3) * 8) ^ ((rl & 3) << 3); // swizzled source col (elems)
  // read-side swizzled column (elems), lane-constant
  const int rcol = (lhi * 8) ^ ((lr & 3) << 3);

  f32x4 acc[4][4];
#pragma unroll
  for (int i = 0; i < 4; i++)
#pragma unroll
    for (int j = 0; j < 4; j++) acc[i][j] = (f32x4){0.f, 0.f, 0.f, 0.f};

  for (int k0 = 0; k0 < DMODEL; k0 += 32) {
#pragma unroll
    for (int i = 0; i < 2; i++) {
      int c = w * 2 + i;
      GLD16(A + (size_t)(m0 + c * 16 + rl) * DMODEL + k0 + scol, &sA[c * 16][0]);
      GLD16(W + (size_t)(n0 + c * 16 + rl) * DMODEL + k0 + scol, &sB[c * 16][0]);
    }
    __syncthreads();
    bf16x8 af[4], bfr[4];
#pragma unroll
    for (int mi = 0; mi < 4; mi++) af[mi] = *(const bf16x8*)(&sA[wr + mi * 16 + lr][rcol]);
#pragma unroll
    for (int ni = 0; ni < 4; ni++) bfr[ni] = *(const bf16x8*)(&sB[wc + ni * 16 + lr][rcol]);
#pragma unroll
    for (int mi = 0; mi < 4; mi++)
#pragma unroll
      for (int ni = 0; ni < 4; ni++)
        acc[mi][ni] = __builtin_amdgcn_mfma_f32_16x16x32_bf16(af[mi], bfr[ni], acc[mi][ni], 0, 0, 0);
    __syncthreads();
  }

  // epilogue: C layout col=lane&15, row=(lane>>4)*4+reg
#pragma unroll
  for (int mi = 0; mi < 4; mi++) {
#pragma unroll
    for (int ni = 0; ni < 4; ni++) {
      int col = n0 + wc + ni * 16 + lr;
      float bsv = bias[col];
      int h = col >> 6, hd = col & 63;
#pragma unroll
      for (int r = 0; r < 4; r++) {
        int row = m0 + wr + mi * 16 + lhi * 4 + r;
        int b = row >> 11, s = row & 2047;
        float vv = acc[mi][ni][r] + bsv;
        out[(((size_t)(b * NH + h)) * SEQ + s) * HD + hd] = f2bf(vv);
      }
    }
  }
}

// ---------------- fallback GEMM (f32 A reg-staged) — used if ws too small ----
__global__ __launch_bounds__(256) void qkv_gemm_f32(
    const float* __restrict__ x0, const float* __restrict__ x1, const float* __restrict__ x2,
    const ushort* __restrict__ Wb,
    const float* __restrict__ bq, const float* __restrict__ bk, const float* __restrict__ bv,
    ushort* __restrict__ qkv) {
  __shared__ ushort sA[128][40];
  __shared__ ushort sB[128][40];

  const int z = blockIdx.z;
  const float* X = z == 0 ? x0 : (z == 1 ? x1 : x2);
  const ushort* W = Wb + (size_t)z * 1048576;
  const float* bias = z == 0 ? bq : (z == 1 ? bk : bv);
  ushort* out = qkv + (size_t)z * QKV_ELEMS;

  const int t = threadIdx.x;
  const int m0 = blockIdx.x * 128;
  const int n0 = blockIdx.y * 128;
  const int w = t >> 6, l = t & 63, lr = l & 15, lhi = l >> 4;
  const int wr = (w >> 1) * 64, wc = (w & 1) * 64;

  f32x4 acc[4][4];
#pragma unroll
  for (int i = 0; i < 4; i++)
#pragma unroll
    for (int j = 0; j < 4; j++) acc[i][j] = (f32x4){0.f, 0.f, 0.f, 0.f};

  for (int k0 = 0; k0 < DMODEL; k0 += 32) {
#pragma unroll
    for (int i = 0; i < 4; i++) {
      int e = i * 256 + t;
      int row = e >> 3, col = (e & 7) * 4;
      float4 a = *(const float4*)(X + (size_t)(m0 + row) * DMODEL + k0 + col);
      ushort4 ab = { f2bf(a.x), f2bf(a.y), f2bf(a.z), f2bf(a.w) };
      *(ushort4*)(&sA[row][col]) = ab;
      ushort4 bb = *(const ushort4*)(W + (size_t)(n0 + row) * DMODEL + k0 + col);
      *(ushort4*)(&sB[row][col]) = bb;
    }
    __syncthreads();
    bf16x8 af[4], bfr[4];
#pragma unroll
    for (int mi = 0; mi < 4; mi++) af[mi] = *(const bf16x8*)(&sA[wr + mi * 16 + lr][lhi * 8]);
#pragma unroll
    for (int ni = 0; ni < 4; ni++) bfr[ni] = *(const bf16x8*)(&sB[wc + ni * 16 + lr][lhi * 8]);
#pragma unroll
    for (int mi = 0; mi < 4; mi++)
#pragma unroll
      for (int ni = 0; ni < 4; ni++)
        acc[mi][ni] = __builtin_amdgcn_mfma_f32_16x16x32_bf16(af[mi], bfr[ni], acc[mi][ni], 0, 0, 0);
    __syncthreads();
  }

#pragma unroll
  for (int mi = 0; mi < 4; mi++) {
#pragma unroll
    for (int ni = 0; ni < 4; ni++) {
      int col = n0 + wc + ni * 16 + lr;
      float bsv = bias[col];
      int h = col >> 6, hd = col & 63;
#pragma unroll
      for (int r = 0; r < 4; r++) {
        int row = m0 + wr + mi * 16 + lhi * 4 + r;
        int b = row >> 11, s = row & 2047;
        float vv = acc[mi][ni][r] + bsv;
        out[(((size_t)(b * NH + h)) * SEQ + s) * HD + hd] = f2bf(vv);
      }
    }
  }
}

// ---------------- flash attention (32x32x16 MFMA, in-register P) ----------------
__global__ __launch_bounds__(256) void attn_kernel(const ushort* __restrict__ qkv,
                                                   float* __restrict__ out) {
  __shared__ ushort Kt[2][64][72];    // K tile  [kv][hd], stride 144B
  __shared__ ushort Vt[2][64][72];    // V^T tile [hd][kv'], kv' = bits2<->3 swapped

  const int rb = blockIdx.x;
  const int bid = (rb & 7) * 128 + (rb >> 3);
  const int bh = bid >> 4, qt = bid & 15;
  const int q0 = qt * 128;
  const int t = threadIdx.x, w = t >> 6, l = t & 63;
  const int lq = l & 31, hi = l >> 5, hi8 = hi * 8;

  const ushort* q = qkv;
  const ushort* k = qkv + QKV_ELEMS;
  const ushort* v = qkv + 2 * (size_t)QKV_ELEMS;
  const size_t base = (size_t)bh * SEQ * HD;

  const int krow = t >> 3, kcol = (t & 7) * 8;
  const int skv = t & 63;
  const int skvp = (skv & 51) | ((skv & 4) << 1) | ((skv & 8) >> 1); // bits 2<->3
  const int shb = (t >> 6) * 8;

  bf16x8 aq[4];
  {
    int qrow = q0 + w * 32 + lq;
#pragma unroll
    for (int ks = 0; ks < 4; ks++)
      aq[ks] = *(const bf16x8*)(q + base + (size_t)qrow * HD + ks * 16 + hi8);
  }

  float m2 = -1e30f, lsum = 0.f;
  f32x16 acc_o[2];
  acc_o[0] = (f32x16)(0.0f);
  acc_o[1] = (f32x16)(0.0f);

#pragma unroll
  for (int i = 0; i < 2; i++) {
    bf16x8 gk = *(const bf16x8*)(k + base + (size_t)(i * 32 + krow) * HD + kcol);
    *(bf16x8*)(&Kt[0][i * 32 + krow][kcol]) = gk;
    bf16x8 gv = *(const bf16x8*)(v + base + (size_t)skv * HD + shb + i * 32);
#pragma unroll
    for (int j = 0; j < 8; j++) Vt[0][shb + i * 32 + j][skvp] = ((ushort)gv[j]);
  }
  __syncthreads();

  for (int tile = 0; tile < SEQ / 64; tile++) {
    const int cur = tile & 1, nxt = cur ^ 1;
    const int kvn = ((tile + 1) & 31) * 64;

    bf16x8 gk[2], gv[2];
#pragma unroll
    for (int i = 0; i < 2; i++) {
      gk[i] = *(const bf16x8*)(k + base + (size_t)(kvn + i * 32 + krow) * HD + kcol);
      gv[i] = *(const bf16x8*)(v + base + (size_t)(kvn + skv) * HD + shb + i * 32);
    }

    f32x16 sc[2];
    sc[0] = (f32x16)(0.0f);
    sc[1] = (f32x16)(0.0f);
#pragma unroll
    for (int mt = 0; mt < 2; mt++)
#pragma unroll
      for (int ks = 0; ks < 4; ks++) {
        bf16x8 ak = *(const bf16x8*)(&Kt[cur][mt * 32 + lq][ks * 16 + hi8]);
        sc[mt] = __builtin_amdgcn_mfma_f32_32x32x16_bf16(ak, aq[ks], sc[mt], 0, 0, 0);
      }

    float tm = sc[0][0];
#pragma unroll
    for (int mt = 0; mt < 2; mt++)
#pragma unroll
      for (int r = 0; r < 16; r++) tm = fmaxf(tm, sc[mt][r]);
    tm *= C2EXP;
    tm = fmaxf(tm, __shfl_xor(tm, 32));
    if (__any(tm > m2 + 8.f)) {
      float mn = fmaxf(m2, tm);
      float alpha = EXP2F(m2 - mn);
      m2 = mn;
      lsum *= alpha;
#pragma unroll
      for (int r = 0; r < 16; r++) {
        int rowq = (r & 3) + 8 * (r >> 2) + 4 * hi;
        float ar = __shfl(alpha, (l & 32) | rowq);
        acc_o[0][r] *= ar;
        acc_o[1][r] *= ar;
      }
    }

    float rs = 0.f;
    unsigned c[2][8];
#pragma unroll
    for (int mt = 0; mt < 2; mt++)
#pragma unroll
      for (int i = 0; i < 8; i++) {
        float p0 = EXP2F(sc[mt][2 * i] * C2EXP - m2);
        float p1 = EXP2F(sc[mt][2 * i + 1] * C2EXP - m2);
        rs += p0 + p1;
        c[mt][i] = pkbf(p0, p1);
      }
    rs += __shfl_xor(rs, 32);
    lsum += rs;

#pragma unroll
    for (int s = 0; s < 4; s++) {
      union { unsigned u[4]; bf16x8 v8; } ap;
#pragma unroll
      for (int j = 0; j < 4; j++) ap.u[j] = c[s >> 1][(s & 1) * 4 + j];
#pragma unroll
      for (int nt = 0; nt < 2; nt++) {
        bf16x8 bv = *(const bf16x8*)(&Vt[cur][nt * 32 + lq][s * 16 + hi8]);
        acc_o[nt] = __builtin_amdgcn_mfma_f32_32x32x16_bf16(ap.v8, bv, acc_o[nt], 0, 0, 0);
      }
    }

#pragma unroll
    for (int i = 0; i < 2; i++) {
      *(bf16x8*)(&Kt[nxt][i * 32 + krow][kcol]) = gk[i];
#pragma unroll
      for (int j = 0; j < 8; j++) Vt[nxt][shb + i * 32 + j][skvp] = ((ushort)gv[i][j]);
    }
    __syncthreads();
  }

  const int b = bh >> 4, h = bh & 15;
  float inv = 1.f / lsum;
#pragma unroll
  for (int r = 0; r < 16; r++) {
    int rowq = (r & 3) + 8 * (r >> 2) + 4 * hi;
    float iv = __shfl(inv, (l & 32) | rowq);
    int s = q0 + w * 32 + rowq;
#pragma unroll
    for (int nt = 0; nt < 2; nt++)
      out[((size_t)(b * SEQ + s)) * DMODEL + h * HD + nt * 32 + lq] = acc_o[nt][r] * iv;
  }
}

extern "C" void kernel_launch(void* const* d_in, const int* in_sizes, int n_in,
                              void* d_out, int out_size, void* d_ws, size_t ws_size,
                              hipStream_t stream) {
  const float* query = (const float*)d_in[0];
  const float* key_  = (const float*)d_in[1];
  const float* value = (const float*)d_in[2];
  const float* Wq = (const float*)d_in[3];
  const float* bq = (const float*)d_in[4];
  const float* Wk = (const float*)d_in[5];
  const float* bk = (const float*)d_in[6];
  const float* Wv = (const float*)d_in[7];
  const float* bv = (const float*)d_in[8];

  ushort* Wb = (ushort*)d_ws;                        // 3 * 1M bf16        (6.3 MB)
  ushort* qkv = Wb + 3u * 1048576u;                  // 3 * 8.39M bf16     (50.3 MB)
  ushort* Xb = qkv + 3u * (size_t)QKV_ELEMS;         // 3 * 8.39M bf16     (50.3 MB)
  const size_t need = (3u * 1048576u + 6u * (size_t)QKV_ELEMS) * 2u;

  convert_w<<<dim3(1024, 3), 256, 0, stream>>>(Wq, Wk, Wv, Wb);
  if (ws_size >= need) {
    convert_x<<<dim3(8192, 3), 256, 0, stream>>>(query, key_, value, Xb);
    qkv_gemm_bf<<<dim3(64, 8, 3), 256, 0, stream>>>(Xb, Wb, bq, bk, bv, qkv);
  } else {
    qkv_gemm_f32<<<dim3(64, 8, 3), 256, 0, stream>>>(query, key_, value, Wb, bq, bk, bv, qkv);
  }
  attn_kernel<<<dim3(BHTOT * (SEQ / 128)), 256, 0, stream>>>(qkv, (float*)d_out);
}